// Round 1
// baseline (469.479 us; speedup 1.0000x reference)
//
#include <hip/hip_runtime.h>

#define DF 64

typedef __attribute__((ext_vector_type(8))) short bf16x8;
typedef __attribute__((ext_vector_type(2))) short v2s;
typedef __attribute__((ext_vector_type(4))) float f32x4;

__device__ __forceinline__ short f2bf(float f) {
    union { float f; unsigned u; } v; v.f = f;
    unsigned u = v.u;
    u += 0x7FFFu + ((u >> 16) & 1u);   // RNE
    return (short)(u >> 16);
}

__device__ __forceinline__ float bf2f(unsigned s) {
    union { unsigned u; float f; } v; v.u = s << 16;
    return v.f;
}

__device__ __forceinline__ bf16x8 cvt8(float4 a, float4 b) {
    bf16x8 r;
    r[0] = f2bf(a.x); r[1] = f2bf(a.y); r[2] = f2bf(a.z); r[3] = f2bf(a.w);
    r[4] = f2bf(b.x); r[5] = f2bf(b.y); r[6] = f2bf(b.z); r[7] = f2bf(b.w);
    return r;
}

// Intra-wave LDS sync: the lsH slices are wave-private, so a full
// __syncthreads() (4-wave block barrier) is unnecessary. A wave executes a
// single instruction stream; lgkmcnt(0) guarantees all prior DS writes by
// this wave have landed before subsequent DS reads. sched_barrier(0) stops
// the compiler hoisting dependent ops above the inline-asm wait (rule #18).
__device__ __forceinline__ void wave_lds_sync() {
    asm volatile("s_waitcnt lgkmcnt(0)" ::: "memory");
    __builtin_amdgcn_sched_barrier(0);
}

// packed bf16x2 atomic add (global_atomic_pk_add_bf16), CAS fallback for safety
__device__ __forceinline__ void pk_add(short* addr, int val) {
#if __has_builtin(__builtin_amdgcn_global_atomic_fadd_v2bf16)
    __builtin_amdgcn_global_atomic_fadd_v2bf16(
        (__attribute__((address_space(1))) v2s*)addr, *(v2s*)&val);
#else
    unsigned* a = (unsigned*)addr;
    unsigned old = *a, assumed;
    do {
        assumed = old;
        float lo = bf2f(assumed & 0xffffu) + bf2f((unsigned)val & 0xffffu);
        float hi = bf2f(assumed >> 16)     + bf2f((unsigned)val >> 16);
        unsigned nv = (unsigned)(unsigned short)f2bf(lo) |
                      ((unsigned)(unsigned short)f2bf(hi) << 16);
        old = atomicCAS(a, assumed, nv);
    } while (old != assumed);
#endif
}

// Transpose + convert the 4 weight matrices to bf16 [n][k] (B^T) once per launch.
__global__ __launch_bounds__(256) void prep_weights(
    const float* __restrict__ w1a, const float* __restrict__ w1b,
    const float* __restrict__ w2a, const float* __restrict__ w2b,
    short* __restrict__ w1aT, short* __restrict__ w1bT,
    short* __restrict__ w2aT, short* __restrict__ w2bT)
{
    int gid = blockIdx.x * 256 + threadIdx.x;   // 24576 total
    if (gid < 8192) {
        int k = gid >> 6, n = gid & 63;
        w1aT[n * 128 + k] = f2bf(w1a[gid]);
    } else if (gid < 12288) {
        int g = gid - 8192; int k = g >> 6, n = g & 63;
        w1bT[n * 64 + k] = f2bf(w1b[g]);
    } else if (gid < 20480) {
        int g = gid - 12288; int k = g >> 6, n = g & 63;
        w2aT[n * 128 + k] = f2bf(w2a[g]);
    } else if (gid < 24576) {
        int g = gid - 20480; int k = g >> 6, n = g & 63;
        w2bT[n * 64 + k] = f2bf(w2b[g]);
    }
}

// Edge MLP + packed-bf16 scatter-add. One 16-edge M-tile per wave.
__global__ __launch_bounds__(256, 8) void edge_mlp_scatter(
    const float* __restrict__ x, const int* __restrict__ ei,
    const float* __restrict__ ea,
    const short* __restrict__ w1aT, const float* __restrict__ b1a,
    const short* __restrict__ w1bT, const float* __restrict__ b1b,
    short* __restrict__ summedh, float* __restrict__ counts, int E)
{
    __shared__ alignas(16) short lsH[4 * 16 * 72];   // 9.2 KB, wave-private slices

    const int t = threadIdx.x;
    const int lane = t & 63;
    const int w = t >> 6;
    const int q = lane >> 4;
    const int m = lane & 15;
    const long base = ((long)blockIdx.x * 4 + w) * 16;

    const long e = base + m;                 // this lane's A-side edge
    const long ec = e < E ? e : (long)(E - 1);
    const int row = ei[ec];

    if (q == 0 && e < E)
        unsafeAtomicAdd(&counts[ei[E + e]], 1.0f);

    // --- A fragments direct from global: concat(x[row], edge_attr[e]) row, bf16
    const float4* xr = (const float4*)(x + (long)row * DF);
    const float4* er = (const float4*)(ea + ec * DF);
    bf16x8 afr[4];
    afr[0] = cvt8(xr[q * 2],     xr[q * 2 + 1]);      // k =      q*8
    afr[1] = cvt8(xr[8 + q * 2], xr[8 + q * 2 + 1]);  // k = 32 + q*8
    afr[2] = cvt8(er[q * 2],     er[q * 2 + 1]);      // k = 64 + q*8
    afr[3] = cvt8(er[8 + q * 2], er[8 + q * 2 + 1]);  // k = 96 + q*8

    // --- GEMM1: [16 x 128] @ [128 x 64], bias init
    f32x4 acc[4];
#pragma unroll
    for (int nt = 0; nt < 4; ++nt) {
        float b = b1a[nt * 16 + m];
        f32x4 v = {b, b, b, b};
        acc[nt] = v;
#pragma unroll
        for (int ks = 0; ks < 4; ++ks) {
            bf16x8 bfr = *(const bf16x8*)&w1aT[(nt * 16 + m) * 128 + ks * 32 + q * 8];
            acc[nt] = __builtin_amdgcn_mfma_f32_16x16x32_bf16(afr[ks], bfr, acc[nt], 0, 0, 0);
        }
    }

    // --- relu, D-layout -> A-layout via wave-private LDS
    short* hw = lsH + w * (16 * 72);
#pragma unroll
    for (int nt = 0; nt < 4; ++nt)
#pragma unroll
        for (int r = 0; r < 4; ++r) {
            float v = acc[nt][r] > 0.f ? acc[nt][r] : 0.f;
            hw[(q * 4 + r) * 72 + nt * 16 + m] = f2bf(v);
        }
    wave_lds_sync();

    bf16x8 a2[2];
    a2[0] = *(const bf16x8*)&hw[m * 72 + q * 8];
    a2[1] = *(const bf16x8*)&hw[m * 72 + 32 + q * 8];

    // --- GEMM2: [16 x 64] @ [64 x 64]
    f32x4 acc2[4];
#pragma unroll
    for (int nt = 0; nt < 4; ++nt) {
        float b = b1b[nt * 16 + m];
        f32x4 v = {b, b, b, b};
        acc2[nt] = v;
#pragma unroll
        for (int ks = 0; ks < 2; ++ks) {
            bf16x8 bfr = *(const bf16x8*)&w1bT[(nt * 16 + m) * 64 + ks * 32 + q * 8];
            acc2[nt] = __builtin_amdgcn_mfma_f32_16x16x32_bf16(a2[ks], bfr, acc2[nt], 0, 0, 0);
        }
    }
    wave_lds_sync();   // stage-1 region fully consumed (intra-wave WAR)

    // --- D-layout -> row-major bf16 pairs in LDS (reuse hw, stride 72 shorts)
#pragma unroll
    for (int nt = 0; nt < 4; ++nt)
#pragma unroll
        for (int r = 0; r < 4; ++r)
            hw[(q * 4 + r) * 72 + nt * 16 + m] = f2bf(acc2[nt][r]);
    wave_lds_sync();

    // --- packed scatter: lane covers pair p of rows (lane>>5)+2i; 8 pk atomics
    const int p = lane & 31;
    const int* hwi = (const int*)hw;
#pragma unroll
    for (int i = 0; i < 8; ++i) {
        int r2 = (lane >> 5) + 2 * i;
        long eg = base + r2;
        if (eg < E) {
            int dst = ei[E + eg];
            int val = hwi[r2 * 36 + p];
            pk_add(&summedh[(long)dst * DF + 2 * p], val);
        }
    }
}

// Node MLP: input = concat(x, summedh/max(counts,1)); writes d_out.
__global__ __launch_bounds__(256, 8) void node_mlp(
    const float* __restrict__ x, const short* __restrict__ summedh,
    const float* __restrict__ counts,
    const short* __restrict__ w2aT, const float* __restrict__ b2a,
    const short* __restrict__ w2bT, const float* __restrict__ b2b,
    float* __restrict__ out, int NN)
{
    __shared__ alignas(16) short lsH[4 * 16 * 72];

    const int t = threadIdx.x;
    const int lane = t & 63;
    const int w = t >> 6;
    const int q = lane >> 4;
    const int m = lane & 15;
    const long base = ((long)blockIdx.x * 4 + w) * 16;

    const long node = base + m;
    const long nc = node < NN ? node : (long)(NN - 1);

    const float4* xr = (const float4*)(x + nc * DF);
    float c = counts[nc];
    c = c > 1.f ? c : 1.f;
    const float inv = 1.f / c;

    bf16x8 s0 = *(const bf16x8*)&summedh[nc * DF + q * 8];
    bf16x8 s1 = *(const bf16x8*)&summedh[nc * DF + 32 + q * 8];

    bf16x8 afr[4];
    afr[0] = cvt8(xr[q * 2],     xr[q * 2 + 1]);
    afr[1] = cvt8(xr[8 + q * 2], xr[8 + q * 2 + 1]);
#pragma unroll
    for (int i = 0; i < 8; ++i) {
        afr[2][i] = f2bf(bf2f((unsigned short)s0[i]) * inv);
        afr[3][i] = f2bf(bf2f((unsigned short)s1[i]) * inv);
    }

    f32x4 acc[4];
#pragma unroll
    for (int nt = 0; nt < 4; ++nt) {
        float b = b2a[nt * 16 + m];
        f32x4 v = {b, b, b, b};
        acc[nt] = v;
#pragma unroll
        for (int ks = 0; ks < 4; ++ks) {
            bf16x8 bfr = *(const bf16x8*)&w2aT[(nt * 16 + m) * 128 + ks * 32 + q * 8];
            acc[nt] = __builtin_amdgcn_mfma_f32_16x16x32_bf16(afr[ks], bfr, acc[nt], 0, 0, 0);
        }
    }

    short* hw = lsH + w * (16 * 72);
#pragma unroll
    for (int nt = 0; nt < 4; ++nt)
#pragma unroll
        for (int r = 0; r < 4; ++r) {
            float v = acc[nt][r] > 0.f ? acc[nt][r] : 0.f;
            hw[(q * 4 + r) * 72 + nt * 16 + m] = f2bf(v);
        }
    wave_lds_sync();

    bf16x8 a2[2];
    a2[0] = *(const bf16x8*)&hw[m * 72 + q * 8];
    a2[1] = *(const bf16x8*)&hw[m * 72 + 32 + q * 8];

    f32x4 acc2[4];
#pragma unroll
    for (int nt = 0; nt < 4; ++nt) {
        float b = b2b[nt * 16 + m];
        f32x4 v = {b, b, b, b};
        acc2[nt] = v;
#pragma unroll
        for (int ks = 0; ks < 2; ++ks) {
            bf16x8 bfr = *(const bf16x8*)&w2bT[(nt * 16 + m) * 64 + ks * 32 + q * 8];
            acc2[nt] = __builtin_amdgcn_mfma_f32_16x16x32_bf16(a2[ks], bfr, acc2[nt], 0, 0, 0);
        }
    }

#pragma unroll
    for (int r = 0; r < 4; ++r) {
        long n2 = base + q * 4 + r;
        if (n2 < NN) {
#pragma unroll
            for (int nt = 0; nt < 4; ++nt)
                out[n2 * DF + nt * 16 + m] = acc2[nt][r];
        }
    }
}

extern "C" void kernel_launch(void* const* d_in, const int* in_sizes, int n_in,
                              void* d_out, int out_size, void* d_ws, size_t ws_size,
                              hipStream_t stream) {
    const float* x   = (const float*)d_in[0];
    const int*   ei  = (const int*)d_in[1];
    const float* ea  = (const float*)d_in[2];
    const float* w1a = (const float*)d_in[5];
    const float* b1a = (const float*)d_in[6];
    const float* w1b = (const float*)d_in[7];
    const float* b1b = (const float*)d_in[8];
    const float* w2a = (const float*)d_in[9];
    const float* b2a = (const float*)d_in[10];
    const float* w2b = (const float*)d_in[11];
    const float* b2b = (const float*)d_in[12];

    const int NN = in_sizes[0] / DF;   // 50000
    const int E  = in_sizes[2] / DF;   // 800000

    char* wsb = (char*)d_ws;
    float* counts  = (float*)wsb;                    // 200 KB (pad to 256 KB)
    short* w1aT    = (short*)(wsb + 262144);         // 16 KB
    short* w1bT    = (short*)(wsb + 278528);         // 8 KB
    short* w2aT    = (short*)(wsb + 286720);         // 16 KB
    short* w2bT    = (short*)(wsb + 303104);         // 8 KB
    short* summedh = (short*)(wsb + 311296);         // 6.4 MB bf16 accumulator

    hipMemsetAsync(counts, 0, (size_t)NN * sizeof(float), stream);
    hipMemsetAsync(summedh, 0, (size_t)NN * DF * sizeof(short), stream);
    prep_weights<<<96, 256, 0, stream>>>(w1a, w1b, w2a, w2b, w1aT, w1bT, w2aT, w2bT);

    int etiles = (E + 15) / 16;
    int eblocks = (etiles + 3) / 4;
    edge_mlp_scatter<<<eblocks, 256, 0, stream>>>(x, ei, ea, w1aT, b1a, w1bT, b1b,
                                                  summedh, counts, E);
    int ntiles = (NN + 15) / 16;
    int nblocks = (ntiles + 3) / 4;
    node_mlp<<<nblocks, 256, 0, stream>>>(x, summedh, counts, w2aT, b2a, w2bT, b2b,
                                          (float*)d_out, NN);
}